// Round 15
// baseline (85.164 us; speedup 1.0000x reference)
//
#include <hip/hip_runtime.h>
#include <hip/hip_bf16.h>
#include <cstdint>

#define LSEQ   2048
#define HID    1024
#define WIN    256
#define MROWS  4096   // B*L

typedef unsigned short u16;
typedef unsigned int   u32;
typedef __attribute__((ext_vector_type(8))) short bf16x8;
typedef __attribute__((ext_vector_type(4))) float f32x4;
typedef __attribute__((address_space(1))) const unsigned int as1_uint;
typedef __attribute__((address_space(3))) unsigned int as3_uint;
typedef __attribute__((address_space(3))) char as3_char;

static __device__ __forceinline__ float bf2f(u16 u) {
  union { u32 u; float f; } c; c.u = ((u32)u) << 16; return c.f;
}
static __device__ __forceinline__ u16 f2bf(float f) {
  union { float f; u32 u; } c; c.f = f;
  u32 r = c.u + 0x7fffu + ((c.u >> 16) & 1u);
  return (u16)(r >> 16);
}

// ---------------- fused fp32->bf16 convert + rope table, one launch ----------------
// tab layout: float2 (cos,sin) interleaved
__global__ void cvt_all(const float* __restrict__ hidden,
                        const float* __restrict__ qw, const float* __restrict__ kw,
                        const float* __restrict__ vw, const float* __restrict__ ow,
                        u16* __restrict__ hbf, u16* __restrict__ wbf,
                        float* __restrict__ tab) {
  const int b = blockIdx.x;
  if (b >= 8192) {
    const int idx = (b - 8192) * 256 + threadIdx.x;   // LSEQ*32
    const int l = idx >> 5, d = idx & 31;
    float invf = exp2f(-(float)d * (13.287712379549449f / 32.0f)); // 10000^(-d/32)
    float ang = (float)l * invf;
    tab[l * 64 + 2 * d]     = cosf(ang);
    tab[l * 64 + 2 * d + 1] = sinf(ang);
    return;
  }
  const int i = b * 256 + threadIdx.x;   // 2M float4 total
  const float* src; u16* dst; int off;
  if (i < (1 << 20)) {
    src = hidden; dst = hbf; off = i;
  } else {
    const int j = i - (1 << 20);
    const int seg = j >> 18;          // 0..3
    off = j & ((1 << 18) - 1);
    src = (seg == 0) ? qw : (seg == 1) ? kw : (seg == 2) ? vw : ow;
    dst = wbf + ((size_t)seg << 20);
  }
  float4 v = ((const float4*)src)[off];
  u32 lo = (u32)f2bf(v.x) | ((u32)f2bf(v.y) << 16);
  u32 hi = (u32)f2bf(v.z) | ((u32)f2bf(v.w) << 16);
  ((uint2*)dst)[off] = make_uint2(lo, hi);
}

// ---------------- 128x128 bf16 GEMM, BK=64, XOR-swizzled LDS (r7/r9-verified): QKV ----------
// Q: rope + softmax pre-scale. K: rope. V: bias -> LDS 128x128 transpose -> coalesced Vt.
__global__ __launch_bounds__(256, 2) void gemm_qkv(
    const u16* __restrict__ A, const u16* __restrict__ W,
    const float* __restrict__ b0, const float* __restrict__ b1, const float* __restrict__ b2,
    u16* __restrict__ outb, const float* __restrict__ tab, u16* __restrict__ vt)
{
  __shared__ u16 SM[2 * 128 * 64];       // As = SM, Bs = SM + 8192; V-transpose reuses all 32 KB
  u16* As = SM;
  u16* Bs = SM + 128 * 64;
  const int tid = threadIdx.x;
  const int lane = tid & 63, w = tid >> 6;
  const int wr = w >> 1, wc = w & 1;
  const int c = lane & 15, g = lane >> 4;

  // XCD swizzle (bijective: 768 % 8 == 0)
  const int GX = 24;
  const int CH = (GX * 32) >> 3;
  int fid = blockIdx.y * GX + blockIdx.x;
  fid = (fid & 7) * CH + (fid >> 3);
  const int bx = fid % GX, by = fid / GX;

  const int srow = tid >> 3;
  const int scolb = ((tid & 7) * 16) ^ ((srow & 7) << 4);
  const char* gA = (const char*)(A + (size_t)(by * 128 + srow) * HID) + scolb;
  const char* gB = (const char*)(W + (size_t)(bx * 128 + srow) * HID) + scolb;

  f32x4 acc[4][4] = {};

  for (int kt = 0; kt < HID; kt += 64) {
    __syncthreads();
    #pragma unroll
    for (int r = 0; r < 4; ++r) {
      __builtin_amdgcn_global_load_lds((as1_uint*)(gA + kt * 2 + r * 32 * (HID * 2)),
                                       (as3_uint*)((as3_char*)As + r * 4096 + w * 1024), 16, 0, 0);
      __builtin_amdgcn_global_load_lds((as1_uint*)(gB + kt * 2 + r * 32 * (HID * 2)),
                                       (as3_uint*)((as3_char*)Bs + r * 4096 + w * 1024), 16, 0, 0);
    }
    __syncthreads();

    const int sw = (c & 7) << 4;
    #pragma unroll
    for (int ks = 0; ks < 2; ++ks) {
      const int colb = (g * 16 + ks * 64);
      bf16x8 af[4], bfr[4];
      #pragma unroll
      for (int mm = 0; mm < 4; ++mm) {
        const int row = wr * 64 + mm * 16 + c;
        af[mm] = *(const bf16x8*)((const char*)As + row * 128 + (colb ^ sw));
      }
      #pragma unroll
      for (int nn = 0; nn < 4; ++nn) {
        const int row = wc * 64 + nn * 16 + c;
        bfr[nn] = *(const bf16x8*)((const char*)Bs + row * 128 + (colb ^ sw));
      }
      #pragma unroll
      for (int mm = 0; mm < 4; ++mm)
        #pragma unroll
        for (int nn = 0; nn < 4; ++nn)
          acc[mm][nn] = __builtin_amdgcn_mfma_f32_16x16x32_bf16(af[mm], bfr[nn], acc[mm][nn], 0, 0, 0);
    }
  }

  const int which = bx >> 3;
  const float* bp = (which == 0) ? b0 : (which == 1 ? b1 : b2);
  const int cb = (bx & 7) * 128;
  u16* ob_ = outb + (size_t)which * MROWS * HID;
  const int rowg = by * 128 + wr * 64;

  #pragma unroll
  for (int nn = 0; nn < 4; ++nn) {
    const float bias = bp[cb + wc * 64 + nn * 16 + c];
    #pragma unroll
    for (int mm = 0; mm < 4; ++mm)
      #pragma unroll
      for (int r = 0; r < 4; ++r) acc[mm][nn][r] += bias;
  }

  if (which < 2) {
    const float QS = (which == 0) ? (0.125f * 1.4426950408889634f) : 1.0f;  // Q pre-scale
    #pragma unroll
    for (int mm = 0; mm < 4; ++mm) {
      #pragma unroll
      for (int r = 0; r < 4; ++r) {
        const int l = (rowg + mm * 16 + (g << 2) + r) & (LSEQ - 1);
        const float2* trow = (const float2*)(tab + l * 64);
        const float2 t0 = trow[c];        // d = c
        const float2 t1 = trow[c + 16];   // d = c + 16
        const float x0 = acc[mm][0][r], y0 = acc[mm][2][r];
        const float x1 = acc[mm][1][r], y1 = acc[mm][3][r];
        acc[mm][0][r] = (x0 * t0.x - y0 * t0.y) * QS;
        acc[mm][2][r] = (y0 * t0.x + x0 * t0.y) * QS;
        acc[mm][1][r] = (x1 * t1.x - y1 * t1.y) * QS;
        acc[mm][3][r] = (y1 * t1.x + x1 * t1.y) * QS;
      }
    }
    #pragma unroll
    for (int nn = 0; nn < 4; ++nn) {
      const int cl = cb + wc * 64 + nn * 16 + c;
      #pragma unroll
      for (int mm = 0; mm < 4; ++mm) {
        const int rb = rowg + mm * 16 + (g << 2);
        #pragma unroll
        for (int r = 0; r < 4; ++r)
          ob_[(size_t)(rb + r) * HID + cl] = f2bf(acc[mm][nn][r]);
      }
    }
  } else {
    // V: acc -> LDS [128 col][128 l] (8-B units XOR-swizzled by (cc&7)<<4) -> coalesced Vt
    u16* Vb = SM;
    __syncthreads();    // all waves done reading As/Bs (block-uniform branch: which = f(bx))
    #pragma unroll
    for (int nn = 0; nn < 4; ++nn) {
      const int cc = wc * 64 + nn * 16 + c;
      const int key = (cc & 7) << 4;
      #pragma unroll
      for (int mm = 0; mm < 4; ++mm) {
        const int ll0 = wr * 64 + mm * 16 + (g << 2);   // l within block (0..124, mult of 4)
        u16 t4[4];
        #pragma unroll
        for (int r = 0; r < 4; ++r) t4[r] = f2bf(acc[mm][nn][r]);
        *(uint2*)((char*)Vb + cc * 256 + ((ll0 * 2) ^ key)) = *(uint2*)t4;
      }
    }
    __syncthreads();
    // store: thread t -> row ri, quarter qf; each stores a CONTIGUOUS 64 B of a Vt row
    const int b_ = by >> 4;
    const int lbase = (by & 15) * 128;
    #pragma unroll
    for (int it = 0; it < 2; ++it) {
      const int ri = (tid >> 2) + it * 64;   // V col within tile = head offset
      const int qf = tid & 3;
      const int key = (ri & 7) << 4;
      const int head = (cb >> 6) + (ri >> 6);
      const int hd = ri & 63;
      uint4 v4[4];
      #pragma unroll
      for (int u = 0; u < 4; ++u)
        v4[u] = *(const uint4*)((const char*)Vb + ri * 256 + ((qf * 64 + u * 16) ^ key));
      u16* dst = vt + (size_t)((b_ * 16 + head) * 64 + hd) * LSEQ + lbase + qf * 32;
      #pragma unroll
      for (int u = 0; u < 4; ++u)
        *(uint4*)(dst + u * 8) = v4[u];
    }
  }
}

// ---------------- 64x128 bf16 GEMM, BK=64 (O-proj, r13-verified): 512 blocks = 2/CU --------
__global__ __launch_bounds__(256, 2) void gemm_o(
    const u16* __restrict__ A, const u16* __restrict__ W,
    const float* __restrict__ b0, float* __restrict__ outf)
{
  __shared__ u16 As[64 * 64];    // 8 KB
  __shared__ u16 Bs[128 * 64];   // 16 KB
  const int tid = threadIdx.x;
  const int lane = tid & 63, w = tid >> 6;   // w = col-wave 0..3 (32 cols each)
  const int c = lane & 15, g = lane >> 4;

  // XCD swizzle: grid (8, 64) = 512 blocks, 64 per XCD (bijective)
  const int GX = 8;
  const int CH = (GX * 64) >> 3;
  int fid = blockIdx.y * GX + blockIdx.x;
  fid = (fid & 7) * CH + (fid >> 3);
  const int bx = fid % GX, by = fid / GX;

  const int srow = tid >> 3;
  const int scolb = ((tid & 7) * 16) ^ ((srow & 7) << 4);
  const char* gA = (const char*)(A + (size_t)(by * 64 + srow) * HID) + scolb;
  const char* gB = (const char*)(W + (size_t)(bx * 128 + srow) * HID) + scolb;

  f32x4 acc[4][2] = {};

  for (int kt = 0; kt < HID; kt += 64) {
    __syncthreads();
    #pragma unroll
    for (int r = 0; r < 2; ++r)   // A: 64 rows in 2 rounds of 32
      __builtin_amdgcn_global_load_lds((as1_uint*)(gA + kt * 2 + r * 32 * (HID * 2)),
                                       (as3_uint*)((as3_char*)As + r * 4096 + w * 1024), 16, 0, 0);
    #pragma unroll
    for (int r = 0; r < 4; ++r)   // B: 128 rows in 4 rounds of 32
      __builtin_amdgcn_global_load_lds((as1_uint*)(gB + kt * 2 + r * 32 * (HID * 2)),
                                       (as3_uint*)((as3_char*)Bs + r * 4096 + w * 1024), 16, 0, 0);
    __syncthreads();

    const int sw = (c & 7) << 4;
    #pragma unroll
    for (int ks = 0; ks < 2; ++ks) {
      const int colb = (g * 16 + ks * 64);
      bf16x8 af[4], bfr[2];
      #pragma unroll
      for (int mm = 0; mm < 4; ++mm) {
        const int row = mm * 16 + c;
        af[mm] = *(const bf16x8*)((const char*)As + row * 128 + (colb ^ sw));
      }
      #pragma unroll
      for (int nn = 0; nn < 2; ++nn) {
        const int row = w * 32 + nn * 16 + c;
        bfr[nn] = *(const bf16x8*)((const char*)Bs + row * 128 + (colb ^ sw));
      }
      #pragma unroll
      for (int mm = 0; mm < 4; ++mm)
        #pragma unroll
        for (int nn = 0; nn < 2; ++nn)
          acc[mm][nn] = __builtin_amdgcn_mfma_f32_16x16x32_bf16(af[mm], bfr[nn], acc[mm][nn], 0, 0, 0);
    }
  }

  const int rowg = by * 64;
  #pragma unroll
  for (int nn = 0; nn < 2; ++nn) {
    const int cl = bx * 128 + w * 32 + nn * 16 + c;
    const float bias = b0[cl];
    #pragma unroll
    for (int mm = 0; mm < 4; ++mm) {
      const int rb = rowg + mm * 16 + (g << 2);
      #pragma unroll
      for (int r = 0; r < 4; ++r)
        outf[(size_t)(rb + r) * HID + cl] = acc[mm][nn][r] + bias;
    }
  }
}

// ---------------- MFMA flash attention: 128 q/block + wave-uniform chunk skip (r14) --------
__global__ __launch_bounds__(512) void attn_mfma(
    const u16* __restrict__ Q, const u16* __restrict__ K,
    const u16* __restrict__ Vt, u16* __restrict__ O)
{
  __shared__ u16 Ks[2 * 64 * 64];  // [buf][k][d'] : LDS[k][cc] = K[k][cc ^ ((k&7)<<4)]
  __shared__ u16 Vs[2 * 64 * 64];  // [buf][d][k'] : same swizzle relation
  __shared__ u16 Ps[8 * 16 * 64];  // per-wave P[q][k]: row q*128, byte = (k*2)^(((q>>2)&3)<<5)

  const int tid = threadIdx.x, lane = tid & 63, w = tid >> 6;
  const int g = lane >> 4, c = lane & 15;
  const int qb = (blockIdx.x & 15) * 128;        // 16 q-blocks of 128 per (b,h)
  const int bh = blockIdx.x >> 4;
  const int h = bh & 15;
  const size_t row0 = (size_t)(bh >> 4) * LSEQ;
  const int qw = qb + w * 16;

  const int srow = (w << 3) + (lane >> 3);
  const int scol = ((lane & 7) * 16) ^ ((lane >> 3) << 4);
  const char* gKb = (const char*)(K + (row0 + srow) * HID + h * 64) + scol;
  const char* gVb = (const char*)(Vt + (size_t)(bh * 64 + srow) * LSEQ) + scol;

  // Q A-frags (pre-scaled by 1/8*log2e in the GEMM epilogue)
  const u16* qptr = Q + (row0 + qw + c) * HID + h * 64 + g * 8;
  bf16x8 qa0 = *(const bf16x8*)qptr;
  bf16x8 qa1 = *(const bf16x8*)(qptr + 32);

  const int cbk = (qb >> 6) + 1;                 // top chunk covers [qb+64, qb+128)
  int cf = (qb - (WIN - 1)) >> 6; if (cf < 0) cf = 0;

  float psum[4] = {0.f, 0.f, 0.f, 0.f};
  f32x4 o_[4];
  #pragma unroll
  for (int dt = 0; dt < 4; ++dt) o_[dt] = f32x4{0.f, 0.f, 0.f, 0.f};

  if (cf > 0) {
    const u16* k0p = K + row0 * HID + h * 64 + g * 8;
    bf16x8 k0a = *(const bf16x8*)k0p;
    bf16x8 k0b = *(const bf16x8*)(k0p + 32);
    float part = 0.f;
    #pragma unroll
    for (int j = 0; j < 8; ++j)
      part += bf2f((u16)qa0[j]) * bf2f((u16)k0a[j]) + bf2f((u16)qa1[j]) * bf2f((u16)k0b[j]);
    part += __shfl_xor(part, 16);
    part += __shfl_xor(part, 32);        // lanes hold s0 for q = qw + (lane&15)
    float p0 = exp2f(part);
    float prs[4];
    #pragma unroll
    for (int r = 0; r < 4; ++r) { prs[r] = __shfl(p0, g * 4 + r); psum[r] = prs[r]; }
    #pragma unroll
    for (int dt = 0; dt < 4; ++dt) {
      float v0 = bf2f(Vt[(size_t)(bh * 64 + dt * 16 + c) * LSEQ]);
      #pragma unroll
      for (int r = 0; r < 4; ++r) o_[dt][r] = prs[r] * v0;
    }
  }

  // stage chunk cf into buf 0 (1 K-load + 1 V-load per wave)
  {
    const size_t kadv = (size_t)cf * 64 * 2048;   // 64 K-rows * 2KB per chunk
    const size_t vadv = (size_t)cf * 128;         // 64 keys * 2B along Vt rows
    __builtin_amdgcn_global_load_lds((as1_uint*)(gKb + kadv), (as3_uint*)((as3_char*)Ks + w * 1024), 16, 0, 0);
    __builtin_amdgcn_global_load_lds((as1_uint*)(gVb + vadv), (as3_uint*)((as3_char*)Vs + w * 1024), 16, 0, 0);
  }

  int buf = 0;
  for (int ci = cf; ci <= cbk; ++ci) {
    const int c0 = ci * 64;
    __syncthreads();   // implicit vmcnt(0): buf's loads landed; prev compute done

    if (ci < cbk) {    // stage next chunk into buf^1 (in flight during compute)
      const size_t kadv = (size_t)(c0 + 64) * 2048;
      const size_t vadv = (size_t)(c0 + 64) * 2;
      __builtin_amdgcn_global_load_lds((as1_uint*)(gKb + kadv),
          (as3_uint*)((as3_char*)Ks + (buf ^ 1) * 8192 + w * 1024), 16, 0, 0);
      __builtin_amdgcn_global_load_lds((as1_uint*)(gVb + vadv),
          (as3_uint*)((as3_char*)Vs + (buf ^ 1) * 8192 + w * 1024), 16, 0, 0);
    }

    // wave-uniform full-mask skip: no valid (q,k) pair for this wave in this chunk
    const bool wave_active = !(c0 > qw + 15) &&
                             !((c0 > 0) && (qw - (c0 + 63) >= WIN));
    if (wave_active) {
      const char* ksbase = (const char*)Ks + buf * 8192;
      const char* vsbase = (const char*)Vs + buf * 8192;

      // QK^T
      f32x4 st[4];
      #pragma unroll
      for (int t = 0; t < 4; ++t) {
        const int krow = t * 16 + c;
        const char* kbase = ksbase + krow * 128;
        const int sw = (krow & 7) << 4;
        bf16x8 kb0 = *(const bf16x8*)(kbase + ((g * 16) ^ sw));
        bf16x8 kb1 = *(const bf16x8*)(kbase + ((g * 16 + 64) ^ sw));
        st[t] = f32x4{0.f, 0.f, 0.f, 0.f};
        st[t] = __builtin_amdgcn_mfma_f32_16x16x32_bf16(qa0, kb0, st[t], 0, 0, 0);
        st[t] = __builtin_amdgcn_mfma_f32_16x16x32_bf16(qa1, kb1, st[t], 0, 0, 0);
      }

      // fixed-max softmax: lane-local exp + lane-local partial sums
      float e[4][4];
      #pragma unroll
      for (int r = 0; r < 4; ++r) {
        const int qi = qw + g * 4 + r;
        #pragma unroll
        for (int t = 0; t < 4; ++t) {
          const int kj = c0 + t * 16 + c;
          const bool valid = (kj <= qi) && ((qi - kj < WIN) || (kj == 0));
          e[r][t] = valid ? exp2f(st[t][r]) : 0.f;
        }
        psum[r] += (e[r][0] + e[r][1]) + (e[r][2] + e[r][3]);
      }

      // P -> per-wave LDS (bf16): row q*128, byte = (k*2) ^ ((q>>2)<<5); q>>2 == g here
      char* pwb = (char*)Ps + w * 2048;
      const int gx = g << 5;
      #pragma unroll
      for (int r = 0; r < 4; ++r) {
        char* prow = pwb + (g * 4 + r) * 128;
        *(u16*)(prow + ((c * 2 + 0)  ^ gx)) = f2bf(e[r][0]);
        *(u16*)(prow + ((c * 2 + 32) ^ gx)) = f2bf(e[r][1]);
        *(u16*)(prow + ((c * 2 + 64) ^ gx)) = f2bf(e[r][2]);
        *(u16*)(prow + ((c * 2 + 96) ^ gx)) = f2bf(e[r][3]);
      }
      asm volatile("s_waitcnt lgkmcnt(0)" ::: "memory");
      __builtin_amdgcn_sched_barrier(0);

      // P A-frags: lane holds P[q=c][k = g*8+j+32kh]; byte = (g*16 + kh*64) ^ ((c>>2)<<5)
      bf16x8 pa[2];
      const int cx = (c >> 2) << 5;
      #pragma unroll
      for (int kh = 0; kh < 2; ++kh) {
        const int inner = (g * 16 + kh * 64) ^ cx;
        pa[kh] = *(const bf16x8*)(pwb + c * 128 + inner);
      }

      // PV
      #pragma unroll
      for (int dt = 0; dt < 4; ++dt) {
        const int drow = dt * 16 + c;
        const char* vbase = vsbase + drow * 128;
        const int sw = (drow & 7) << 4;
        bf16x8 vb0 = *(const bf16x8*)(vbase + ((g * 16) ^ sw));
        bf16x8 vb1 = *(const bf16x8*)(vbase + ((g * 16 + 64) ^ sw));
        o_[dt] = __builtin_amdgcn_mfma_f32_16x16x32_bf16(pa[0], vb0, o_[dt], 0, 0, 0);
        o_[dt] = __builtin_amdgcn_mfma_f32_16x16x32_bf16(pa[1], vb1, o_[dt], 0, 0, 0);
      }
    }
    buf ^= 1;
  }

  #pragma unroll
  for (int r = 0; r < 4; ++r) {
    #pragma unroll
    for (int off = 1; off < 16; off <<= 1) psum[r] += __shfl_xor(psum[r], off);
  }

  #pragma unroll
  for (int r = 0; r < 4; ++r) {
    const float inv = 1.f / psum[r];
    u16* orow = O + (row0 + qw + g * 4 + r) * HID + h * 64;
    #pragma unroll
    for (int dt = 0; dt < 4; ++dt)
      orow[dt * 16 + c] = f2bf(o_[dt][r] * inv);
  }
}

// ---------------- launch ----------------
extern "C" void kernel_launch(void* const* d_in, const int* in_sizes, int n_in,
                              void* d_out, int out_size, void* d_ws, size_t ws_size,
                              hipStream_t stream) {
  const float* hidden = (const float*)d_in[0];
  const float* qw = (const float*)d_in[1];
  const float* qb = (const float*)d_in[2];
  const float* kw = (const float*)d_in[3];
  const float* kb = (const float*)d_in[4];
  const float* vw = (const float*)d_in[5];
  const float* vb = (const float*)d_in[6];
  const float* ow = (const float*)d_in[7];
  const float* ob = (const float*)d_in[8];
  float* out = (float*)d_out;

  u16* hbf = (u16*)d_ws;
  u16* wbf = hbf + (size_t)MROWS * HID;
  u16* qkv = wbf + (size_t)4 * HID * HID;
  float* tab = (float*)(qkv + (size_t)3 * MROWS * HID);
  u16* Vt = (u16*)(tab + (size_t)LSEQ * 64);

  cvt_all<<<8448, 256, 0, stream>>>(hidden, qw, kw, vw, ow, hbf, wbf, tab);

  gemm_qkv<<<dim3(24, 32), 256, 0, stream>>>(hbf, wbf, qb, kb, vb, qkv, tab, Vt);
  attn_mfma<<<512, 512, 0, stream>>>(qkv, qkv + (size_t)MROWS * HID, Vt, qkv);
  gemm_o<<<dim3(8, 64), 256, 0, stream>>>(qkv, wbf + (size_t)3 * HID * HID, ob, out);
}

// Round 16
// 84.801 us; speedup vs baseline: 1.0043x; 1.0043x over previous
//
#include <hip/hip_runtime.h>
#include <hip/hip_bf16.h>
#include <cstdint>

#define LSEQ   2048
#define HID    1024
#define WIN    256
#define MROWS  4096   // B*L

typedef unsigned short u16;
typedef unsigned int   u32;
typedef __attribute__((ext_vector_type(8))) short bf16x8;
typedef __attribute__((ext_vector_type(4))) float f32x4;
typedef __attribute__((address_space(1))) const unsigned int as1_uint;
typedef __attribute__((address_space(3))) unsigned int as3_uint;
typedef __attribute__((address_space(3))) char as3_char;

static __device__ __forceinline__ float bf2f(u16 u) {
  union { u32 u; float f; } c; c.u = ((u32)u) << 16; return c.f;
}
static __device__ __forceinline__ u16 f2bf(float f) {
  union { float f; u32 u; } c; c.f = f;
  u32 r = c.u + 0x7fffu + ((c.u >> 16) & 1u);
  return (u16)(r >> 16);
}

// ---------------- fused fp32->bf16 convert + rope table, one launch ----------------
// tab layout: float2 (cos,sin) interleaved
__global__ void cvt_all(const float* __restrict__ hidden,
                        const float* __restrict__ qw, const float* __restrict__ kw,
                        const float* __restrict__ vw, const float* __restrict__ ow,
                        u16* __restrict__ hbf, u16* __restrict__ wbf,
                        float* __restrict__ tab) {
  const int b = blockIdx.x;
  if (b >= 8192) {
    const int idx = (b - 8192) * 256 + threadIdx.x;   // LSEQ*32
    const int l = idx >> 5, d = idx & 31;
    float invf = exp2f(-(float)d * (13.287712379549449f / 32.0f)); // 10000^(-d/32)
    float ang = (float)l * invf;
    tab[l * 64 + 2 * d]     = cosf(ang);
    tab[l * 64 + 2 * d + 1] = sinf(ang);
    return;
  }
  const int i = b * 256 + threadIdx.x;   // 2M float4 total
  const float* src; u16* dst; int off;
  if (i < (1 << 20)) {
    src = hidden; dst = hbf; off = i;
  } else {
    const int j = i - (1 << 20);
    const int seg = j >> 18;          // 0..3
    off = j & ((1 << 18) - 1);
    src = (seg == 0) ? qw : (seg == 1) ? kw : (seg == 2) ? vw : ow;
    dst = wbf + ((size_t)seg << 20);
  }
  float4 v = ((const float4*)src)[off];
  u32 lo = (u32)f2bf(v.x) | ((u32)f2bf(v.y) << 16);
  u32 hi = (u32)f2bf(v.z) | ((u32)f2bf(v.w) << 16);
  ((uint2*)dst)[off] = make_uint2(lo, hi);
}

// ---------------- 128x128 bf16 GEMM, BK=64, XOR-swizzled LDS (r7/r9-verified): QKV ----------
// Q: rope + softmax pre-scale. K: rope. V: written transposed to Vt (direct, r14).
// launch_bounds(256,3): cap VGPR ~170 so 3 blocks/CU co-reside (m114 wave-overlap).
__global__ __launch_bounds__(256, 3) void gemm_qkv(
    const u16* __restrict__ A, const u16* __restrict__ W,
    const float* __restrict__ b0, const float* __restrict__ b1, const float* __restrict__ b2,
    u16* __restrict__ outb, const float* __restrict__ tab, u16* __restrict__ vt)
{
  __shared__ u16 As[128 * 64];
  __shared__ u16 Bs[128 * 64];
  const int tid = threadIdx.x;
  const int lane = tid & 63, w = tid >> 6;
  const int wr = w >> 1, wc = w & 1;
  const int c = lane & 15, g = lane >> 4;

  // XCD swizzle (bijective: 768 % 8 == 0)
  const int GX = 24;
  const int CH = (GX * 32) >> 3;
  int fid = blockIdx.y * GX + blockIdx.x;
  fid = (fid & 7) * CH + (fid >> 3);
  const int bx = fid % GX, by = fid / GX;

  const int srow = tid >> 3;
  const int scolb = ((tid & 7) * 16) ^ ((srow & 7) << 4);
  const char* gA = (const char*)(A + (size_t)(by * 128 + srow) * HID) + scolb;
  const char* gB = (const char*)(W + (size_t)(bx * 128 + srow) * HID) + scolb;

  f32x4 acc[4][4] = {};

  for (int kt = 0; kt < HID; kt += 64) {
    __syncthreads();
    #pragma unroll
    for (int r = 0; r < 4; ++r) {
      __builtin_amdgcn_global_load_lds((as1_uint*)(gA + kt * 2 + r * 32 * (HID * 2)),
                                       (as3_uint*)((as3_char*)As + r * 4096 + w * 1024), 16, 0, 0);
      __builtin_amdgcn_global_load_lds((as1_uint*)(gB + kt * 2 + r * 32 * (HID * 2)),
                                       (as3_uint*)((as3_char*)Bs + r * 4096 + w * 1024), 16, 0, 0);
    }
    __syncthreads();

    const int sw = (c & 7) << 4;
    #pragma unroll
    for (int ks = 0; ks < 2; ++ks) {
      const int colb = (g * 16 + ks * 64);
      bf16x8 af[4], bfr[4];
      #pragma unroll
      for (int mm = 0; mm < 4; ++mm) {
        const int row = wr * 64 + mm * 16 + c;
        af[mm] = *(const bf16x8*)((const char*)As + row * 128 + (colb ^ sw));
      }
      #pragma unroll
      for (int nn = 0; nn < 4; ++nn) {
        const int row = wc * 64 + nn * 16 + c;
        bfr[nn] = *(const bf16x8*)((const char*)Bs + row * 128 + (colb ^ sw));
      }
      #pragma unroll
      for (int mm = 0; mm < 4; ++mm)
        #pragma unroll
        for (int nn = 0; nn < 4; ++nn)
          acc[mm][nn] = __builtin_amdgcn_mfma_f32_16x16x32_bf16(af[mm], bfr[nn], acc[mm][nn], 0, 0, 0);
    }
  }

  const int which = bx >> 3;
  const float* bp = (which == 0) ? b0 : (which == 1 ? b1 : b2);
  const int cb = (bx & 7) * 128;
  u16* ob_ = outb + (size_t)which * MROWS * HID;
  const int rowg = by * 128 + wr * 64;

  #pragma unroll
  for (int nn = 0; nn < 4; ++nn) {
    const float bias = bp[cb + wc * 64 + nn * 16 + c];
    #pragma unroll
    for (int mm = 0; mm < 4; ++mm)
      #pragma unroll
      for (int r = 0; r < 4; ++r) acc[mm][nn][r] += bias;
  }

  if (which < 2) {
    const float QS = (which == 0) ? (0.125f * 1.4426950408889634f) : 1.0f;  // Q pre-scale
    #pragma unroll
    for (int mm = 0; mm < 4; ++mm) {
      #pragma unroll
      for (int r = 0; r < 4; ++r) {
        const int l = (rowg + mm * 16 + (g << 2) + r) & (LSEQ - 1);
        const float2* trow = (const float2*)(tab + l * 64);
        const float2 t0 = trow[c];        // d = c
        const float2 t1 = trow[c + 16];   // d = c + 16
        const float x0 = acc[mm][0][r], y0 = acc[mm][2][r];
        const float x1 = acc[mm][1][r], y1 = acc[mm][3][r];
        acc[mm][0][r] = (x0 * t0.x - y0 * t0.y) * QS;
        acc[mm][2][r] = (y0 * t0.x + x0 * t0.y) * QS;
        acc[mm][1][r] = (x1 * t1.x - y1 * t1.y) * QS;
        acc[mm][3][r] = (y1 * t1.x + x1 * t1.y) * QS;
      }
    }
    #pragma unroll
    for (int nn = 0; nn < 4; ++nn) {
      const int cl = cb + wc * 64 + nn * 16 + c;
      #pragma unroll
      for (int mm = 0; mm < 4; ++mm) {
        const int rb = rowg + mm * 16 + (g << 2);
        #pragma unroll
        for (int r = 0; r < 4; ++r)
          ob_[(size_t)(rb + r) * HID + cl] = f2bf(acc[mm][nn][r]);
      }
    }
  } else {
    #pragma unroll
    for (int nn = 0; nn < 4; ++nn) {
      const int cl = cb + wc * 64 + nn * 16 + c;
      const int hh = cl >> 6, hd = cl & 63;
      #pragma unroll
      for (int mm = 0; mm < 4; ++mm) {
        const int rb = rowg + mm * 16 + (g << 2);
        const int b_ = rb >> 11, l = rb & (LSEQ - 1);
        u16 t4[4];
        #pragma unroll
        for (int r = 0; r < 4; ++r) t4[r] = f2bf(acc[mm][nn][r]);
        *(uint2*)&vt[(size_t)((b_ * 16 + hh) * 64 + hd) * LSEQ + l] = *(uint2*)t4;
      }
    }
  }
}

// ---------------- 64x128 bf16 GEMM, BK=64 (O-proj, r13-verified): 512 blocks ---------------
__global__ __launch_bounds__(256, 3) void gemm_o(
    const u16* __restrict__ A, const u16* __restrict__ W,
    const float* __restrict__ b0, float* __restrict__ outf)
{
  __shared__ u16 As[64 * 64];    // 8 KB
  __shared__ u16 Bs[128 * 64];   // 16 KB
  const int tid = threadIdx.x;
  const int lane = tid & 63, w = tid >> 6;   // w = col-wave 0..3 (32 cols each)
  const int c = lane & 15, g = lane >> 4;

  // XCD swizzle: grid (8, 64) = 512 blocks, 64 per XCD (bijective)
  const int GX = 8;
  const int CH = (GX * 64) >> 3;
  int fid = blockIdx.y * GX + blockIdx.x;
  fid = (fid & 7) * CH + (fid >> 3);
  const int bx = fid % GX, by = fid / GX;

  const int srow = tid >> 3;
  const int scolb = ((tid & 7) * 16) ^ ((srow & 7) << 4);
  const char* gA = (const char*)(A + (size_t)(by * 64 + srow) * HID) + scolb;
  const char* gB = (const char*)(W + (size_t)(bx * 128 + srow) * HID) + scolb;

  f32x4 acc[4][2] = {};

  for (int kt = 0; kt < HID; kt += 64) {
    __syncthreads();
    #pragma unroll
    for (int r = 0; r < 2; ++r)   // A: 64 rows in 2 rounds of 32
      __builtin_amdgcn_global_load_lds((as1_uint*)(gA + kt * 2 + r * 32 * (HID * 2)),
                                       (as3_uint*)((as3_char*)As + r * 4096 + w * 1024), 16, 0, 0);
    #pragma unroll
    for (int r = 0; r < 4; ++r)   // B: 128 rows in 4 rounds of 32
      __builtin_amdgcn_global_load_lds((as1_uint*)(gB + kt * 2 + r * 32 * (HID * 2)),
                                       (as3_uint*)((as3_char*)Bs + r * 4096 + w * 1024), 16, 0, 0);
    __syncthreads();

    const int sw = (c & 7) << 4;
    #pragma unroll
    for (int ks = 0; ks < 2; ++ks) {
      const int colb = (g * 16 + ks * 64);
      bf16x8 af[4], bfr[2];
      #pragma unroll
      for (int mm = 0; mm < 4; ++mm) {
        const int row = mm * 16 + c;
        af[mm] = *(const bf16x8*)((const char*)As + row * 128 + (colb ^ sw));
      }
      #pragma unroll
      for (int nn = 0; nn < 2; ++nn) {
        const int row = w * 32 + nn * 16 + c;
        bfr[nn] = *(const bf16x8*)((const char*)Bs + row * 128 + (colb ^ sw));
      }
      #pragma unroll
      for (int mm = 0; mm < 4; ++mm)
        #pragma unroll
        for (int nn = 0; nn < 2; ++nn)
          acc[mm][nn] = __builtin_amdgcn_mfma_f32_16x16x32_bf16(af[mm], bfr[nn], acc[mm][nn], 0, 0, 0);
    }
  }

  const int rowg = by * 64;
  #pragma unroll
  for (int nn = 0; nn < 2; ++nn) {
    const int cl = bx * 128 + w * 32 + nn * 16 + c;
    const float bias = b0[cl];
    #pragma unroll
    for (int mm = 0; mm < 4; ++mm) {
      const int rb = rowg + mm * 16 + (g << 2);
      #pragma unroll
      for (int r = 0; r < 4; ++r)
        outf[(size_t)(rb + r) * HID + cl] = acc[mm][nn][r] + bias;
    }
  }
}

// ---------------- MFMA flash attention: 128 q/block + wave-uniform chunk skip (r14) --------
__global__ __launch_bounds__(512) void attn_mfma(
    const u16* __restrict__ Q, const u16* __restrict__ K,
    const u16* __restrict__ Vt, u16* __restrict__ O)
{
  __shared__ u16 Ks[2 * 64 * 64];  // [buf][k][d'] : LDS[k][cc] = K[k][cc ^ ((k&7)<<4)]
  __shared__ u16 Vs[2 * 64 * 64];  // [buf][d][k'] : same swizzle relation
  __shared__ u16 Ps[8 * 16 * 64];  // per-wave P[q][k]: row q*128, byte = (k*2)^(((q>>2)&3)<<5)

  const int tid = threadIdx.x, lane = tid & 63, w = tid >> 6;
  const int g = lane >> 4, c = lane & 15;
  const int qb = (blockIdx.x & 15) * 128;        // 16 q-blocks of 128 per (b,h)
  const int bh = blockIdx.x >> 4;
  const int h = bh & 15;
  const size_t row0 = (size_t)(bh >> 4) * LSEQ;
  const int qw = qb + w * 16;

  const int srow = (w << 3) + (lane >> 3);
  const int scol = ((lane & 7) * 16) ^ ((lane >> 3) << 4);
  const char* gKb = (const char*)(K + (row0 + srow) * HID + h * 64) + scol;
  const char* gVb = (const char*)(Vt + (size_t)(bh * 64 + srow) * LSEQ) + scol;

  // Q A-frags (pre-scaled by 1/8*log2e in the GEMM epilogue)
  const u16* qptr = Q + (row0 + qw + c) * HID + h * 64 + g * 8;
  bf16x8 qa0 = *(const bf16x8*)qptr;
  bf16x8 qa1 = *(const bf16x8*)(qptr + 32);

  const int cbk = (qb >> 6) + 1;                 // top chunk covers [qb+64, qb+128)
  int cf = (qb - (WIN - 1)) >> 6; if (cf < 0) cf = 0;

  float psum[4] = {0.f, 0.f, 0.f, 0.f};
  f32x4 o_[4];
  #pragma unroll
  for (int dt = 0; dt < 4; ++dt) o_[dt] = f32x4{0.f, 0.f, 0.f, 0.f};

  if (cf > 0) {
    const u16* k0p = K + row0 * HID + h * 64 + g * 8;
    bf16x8 k0a = *(const bf16x8*)k0p;
    bf16x8 k0b = *(const bf16x8*)(k0p + 32);
    float part = 0.f;
    #pragma unroll
    for (int j = 0; j < 8; ++j)
      part += bf2f((u16)qa0[j]) * bf2f((u16)k0a[j]) + bf2f((u16)qa1[j]) * bf2f((u16)k0b[j]);
    part += __shfl_xor(part, 16);
    part += __shfl_xor(part, 32);        // lanes hold s0 for q = qw + (lane&15)
    float p0 = exp2f(part);
    float prs[4];
    #pragma unroll
    for (int r = 0; r < 4; ++r) { prs[r] = __shfl(p0, g * 4 + r); psum[r] = prs[r]; }
    #pragma unroll
    for (int dt = 0; dt < 4; ++dt) {
      float v0 = bf2f(Vt[(size_t)(bh * 64 + dt * 16 + c) * LSEQ]);
      #pragma unroll
      for (int r = 0; r < 4; ++r) o_[dt][r] = prs[r] * v0;
    }
  }

  // stage chunk cf into buf 0 (1 K-load + 1 V-load per wave)
  {
    const size_t kadv = (size_t)cf * 64 * 2048;   // 64 K-rows * 2KB per chunk
    const size_t vadv = (size_t)cf * 128;         // 64 keys * 2B along Vt rows
    __builtin_amdgcn_global_load_lds((as1_uint*)(gKb + kadv), (as3_uint*)((as3_char*)Ks + w * 1024), 16, 0, 0);
    __builtin_amdgcn_global_load_lds((as1_uint*)(gVb + vadv), (as3_uint*)((as3_char*)Vs + w * 1024), 16, 0, 0);
  }

  int buf = 0;
  for (int ci = cf; ci <= cbk; ++ci) {
    const int c0 = ci * 64;
    __syncthreads();   // implicit vmcnt(0): buf's loads landed; prev compute done

    if (ci < cbk) {    // stage next chunk into buf^1 (in flight during compute)
      const size_t kadv = (size_t)(c0 + 64) * 2048;
      const size_t vadv = (size_t)(c0 + 64) * 2;
      __builtin_amdgcn_global_load_lds((as1_uint*)(gKb + kadv),
          (as3_uint*)((as3_char*)Ks + (buf ^ 1) * 8192 + w * 1024), 16, 0, 0);
      __builtin_amdgcn_global_load_lds((as1_uint*)(gVb + vadv),
          (as3_uint*)((as3_char*)Vs + (buf ^ 1) * 8192 + w * 1024), 16, 0, 0);
    }

    // wave-uniform full-mask skip: no valid (q,k) pair for this wave in this chunk
    const bool wave_active = !(c0 > qw + 15) &&
                             !((c0 > 0) && (qw - (c0 + 63) >= WIN));
    if (wave_active) {
      const char* ksbase = (const char*)Ks + buf * 8192;
      const char* vsbase = (const char*)Vs + buf * 8192;

      // QK^T
      f32x4 st[4];
      #pragma unroll
      for (int t = 0; t < 4; ++t) {
        const int krow = t * 16 + c;
        const char* kbase = ksbase + krow * 128;
        const int sw = (krow & 7) << 4;
        bf16x8 kb0 = *(const bf16x8*)(kbase + ((g * 16) ^ sw));
        bf16x8 kb1 = *(const bf16x8*)(kbase + ((g * 16 + 64) ^ sw));
        st[t] = f32x4{0.f, 0.f, 0.f, 0.f};
        st[t] = __builtin_amdgcn_mfma_f32_16x16x32_bf16(qa0, kb0, st[t], 0, 0, 0);
        st[t] = __builtin_amdgcn_mfma_f32_16x16x32_bf16(qa1, kb1, st[t], 0, 0, 0);
      }

      // fixed-max softmax: lane-local exp + lane-local partial sums
      float e[4][4];
      #pragma unroll
      for (int r = 0; r < 4; ++r) {
        const int qi = qw + g * 4 + r;
        #pragma unroll
        for (int t = 0; t < 4; ++t) {
          const int kj = c0 + t * 16 + c;
          const bool valid = (kj <= qi) && ((qi - kj < WIN) || (kj == 0));
          e[r][t] = valid ? exp2f(st[t][r]) : 0.f;
        }
        psum[r] += (e[r][0] + e[r][1]) + (e[r][2] + e[r][3]);
      }

      // P -> per-wave LDS (bf16): row q*128, byte = (k*2) ^ ((q>>2)<<5); q>>2 == g here
      char* pwb = (char*)Ps + w * 2048;
      const int gx = g << 5;
      #pragma unroll
      for (int r = 0; r < 4; ++r) {
        char* prow = pwb + (g * 4 + r) * 128;
        *(u16*)(prow + ((c * 2 + 0)  ^ gx)) = f2bf(e[r][0]);
        *(u16*)(prow + ((c * 2 + 32) ^ gx)) = f2bf(e[r][1]);
        *(u16*)(prow + ((c * 2 + 64) ^ gx)) = f2bf(e[r][2]);
        *(u16*)(prow + ((c * 2 + 96) ^ gx)) = f2bf(e[r][3]);
      }
      asm volatile("s_waitcnt lgkmcnt(0)" ::: "memory");
      __builtin_amdgcn_sched_barrier(0);

      // P A-frags: lane holds P[q=c][k = g*8+j+32kh]; byte = (g*16 + kh*64) ^ ((c>>2)<<5)
      bf16x8 pa[2];
      const int cx = (c >> 2) << 5;
      #pragma unroll
      for (int kh = 0; kh < 2; ++kh) {
        const int inner = (g * 16 + kh * 64) ^ cx;
        pa[kh] = *(const bf16x8*)(pwb + c * 128 + inner);
      }

      // PV
      #pragma unroll
      for (int dt = 0; dt < 4; ++dt) {
        const int drow = dt * 16 + c;
        const char* vbase = vsbase + drow * 128;
        const int sw = (drow & 7) << 4;
        bf16x8 vb0 = *(const bf16x8*)(vbase + ((g * 16) ^ sw));
        bf16x8 vb1 = *(const bf16x8*)(vbase + ((g * 16 + 64) ^ sw));
        o_[dt] = __builtin_amdgcn_mfma_f32_16x16x32_bf16(pa[0], vb0, o_[dt], 0, 0, 0);
        o_[dt] = __builtin_amdgcn_mfma_f32_16x16x32_bf16(pa[1], vb1, o_[dt], 0, 0, 0);
      }
    }
    buf ^= 1;
  }

  #pragma unroll
  for (int r = 0; r < 4; ++r) {
    #pragma unroll
    for (int off = 1; off < 16; off <<= 1) psum[r] += __shfl_xor(psum[r], off);
  }

  #pragma unroll
  for (int r = 0; r < 4; ++r) {
    const float inv = 1.f / psum[r];
    u16* orow = O + (row0 + qw + g * 4 + r) * HID + h * 64;
    #pragma unroll
    for (int dt = 0; dt < 4; ++dt)
      orow[dt * 16 + c] = f2bf(o_[dt][r] * inv);
  }
}

// ---------------- launch ----------------
extern "C" void kernel_launch(void* const* d_in, const int* in_sizes, int n_in,
                              void* d_out, int out_size, void* d_ws, size_t ws_size,
                              hipStream_t stream) {
  const float* hidden = (const float*)d_in[0];
  const float* qw = (const float*)d_in[1];
  const float* qb = (const float*)d_in[2];
  const float* kw = (const float*)d_in[3];
  const float* kb = (const float*)d_in[4];
  const float* vw = (const float*)d_in[5];
  const float* vb = (const float*)d_in[6];
  const float* ow = (const float*)d_in[7];
  const float* ob = (const float*)d_in[8];
  float* out = (float*)d_out;

  u16* hbf = (u16*)d_ws;
  u16* wbf = hbf + (size_t)MROWS * HID;
  u16* qkv = wbf + (size_t)4 * HID * HID;
  float* tab = (float*)(qkv + (size_t)3 * MROWS * HID);
  u16* Vt = (u16*)(tab + (size_t)LSEQ * 64);

  cvt_all<<<8448, 256, 0, stream>>>(hidden, qw, kw, vw, ow, hbf, wbf, tab);

  gemm_qkv<<<dim3(24, 32), 256, 0, stream>>>(hbf, wbf, qb, kb, vb, qkv, tab, Vt);
  attn_mfma<<<512, 512, 0, stream>>>(qkv, qkv + (size_t)MROWS * HID, Vt, qkv);
  gemm_o<<<dim3(8, 64), 256, 0, stream>>>(qkv, wbf + (size_t)3 * HID * HID, ob, out);
}